// Round 2
// baseline (13638.876 us; speedup 1.0000x reference)
//
#include <hip/hip_runtime.h>
#include <hip/hip_bf16.h>
#include <cstdint>

// ---------------------------------------------------------------------------
// BiLSTM: x[2048,1024] -> bidirectional LSTM (H=1024) -> FC to 1000 classes.
// Strategy:
//   1. convert_all: fp32 -> f16 copies of x, W_ih_f, W_ih_b, fc_W (padded to 1024 rows)
//   2. gemm_f16<0>: x_proj_d = x_d @ W_ih_d^T + b_ih + b_hh   (f16 MFMA, f16 out)
//   3. lstm_rec: persistent kernel, 128 blocks (64/dir), W_hh in registers (f16),
//      flag-based producer/consumer sync per timestep (agent-scope atomics)
//   4. gemm_f16<1>: out = h_hist @ fc_W^T + fc_b               (fp32 out)
// NOTE: all f16 VECTOR types must be __fp16-based (clang builtin signatures);
// _Float16 vectors are a distinct, non-convertible type (R1 compile failure).
// ---------------------------------------------------------------------------

typedef __fp16 h2 __attribute__((ext_vector_type(2)));
typedef __fp16 h8 __attribute__((ext_vector_type(8)));
typedef float f4 __attribute__((ext_vector_type(4)));

#define T_LEN 2048
#define HDIM  1024

static __device__ __forceinline__ unsigned int packh2(float a, float b) {
  h2 r = __builtin_amdgcn_cvt_pkrtz(a, b);
  return __builtin_bit_cast(unsigned int, r);
}
static __device__ __forceinline__ float fdot2u(unsigned int a, unsigned int b, float c) {
  return __builtin_amdgcn_fdot2(__builtin_bit_cast(h2, a), __builtin_bit_cast(h2, b), c, false);
}
static __device__ __forceinline__ float sigmoidf_(float x) {
  return 1.f / (1.f + __expf(-x));
}
static __device__ __forceinline__ float tanhf_(float x) {
  float e = __expf(-2.f * fabsf(x));
  float r = (1.f - e) / (1.f + e);
  return copysignf(r, x);
}

// ---------------------------------------------------------------------------
// convert fp32 inputs to f16 working copies
// ---------------------------------------------------------------------------
__global__ void convert_all(const float* __restrict__ x, const float* __restrict__ wf,
                            const float* __restrict__ wb, const float* __restrict__ fcw,
                            _Float16* __restrict__ xf, _Float16* __restrict__ wff,
                            _Float16* __restrict__ wbf, _Float16* __restrict__ fcwf) {
  const size_t SX = 2097152, SW = 4194304, SFC = 2097152;
  size_t i = (size_t)blockIdx.x * 256 + threadIdx.x;
  if (i < SX) {
    xf[i] = (_Float16)x[i];
  } else if (i < SX + SW) {
    size_t j = i - SX; wff[j] = (_Float16)wf[j];
  } else if (i < SX + 2 * SW) {
    size_t j = i - SX - SW; wbf[j] = (_Float16)wb[j];
  } else if (i < SX + 2 * SW + SFC) {
    size_t j = i - SX - 2 * SW;
    int row = (int)(j >> 11), col = (int)(j & 2047);
    fcwf[j] = (row < 1000) ? (_Float16)fcw[(size_t)row * 2048 + col] : (_Float16)0.f;
  }
}

// zero ping-pong h buffers + flags
__global__ void init_state(float* __restrict__ hbuf, int* __restrict__ flags) {
  int t = threadIdx.x;
  if (t < 128) flags[t] = 0;
  for (int i = t; i < 4096; i += 256) hbuf[i] = 0.f;
}

// ---------------------------------------------------------------------------
// Generic f16 GEMM: C[m][n] = sum_k A[m][k]*B[n][k] (+bias), 128x128 tile, BK=64
// MODE 0: proj (f16 out, bias1+bias2, optional reversed A rows)
// MODE 1: fc   (fp32 out to d_out, bias1, store guard n<nout, out stride nout)
// MFMA 16x16x32_f16 layouts (m89/m120-verified):
//   a/b frag: lane l holds X[l&15][k0 + (l>>4)*8 + j], j=0..7
//   d: reg r, lane l -> row m=(l>>4)*4+r, col n=l&15
// ---------------------------------------------------------------------------
#define LSTR 80  // LDS row stride in f16 (64 + 16 pad, keeps 16B alignment)

template <int MODE>
__global__ __launch_bounds__(256, 2) void gemm_f16(
    const _Float16* __restrict__ A, const _Float16* __restrict__ B,
    const float* __restrict__ bias1, const float* __restrict__ bias2,
    void* __restrict__ Cout, int M, int N, int K, int nout, int rev) {
  __shared__ _Float16 As[128 * LSTR];
  __shared__ _Float16 Bs[128 * LSTR];

  const int tid = threadIdx.x;
  const int ntn = N >> 7;
  const int tm = blockIdx.x / ntn, tn = blockIdx.x % ntn;
  const int wid = tid >> 6, lane = tid & 63;
  const int wr = wid >> 1, wc = wid & 1;
  const int quad = lane >> 4, l16 = lane & 15;

  const int srow = tid >> 1, seg = tid & 1;  // staging: row 0..127, 32-f16 half
  const int arow = rev ? (M - 1 - (tm * 128 + srow)) : (tm * 128 + srow);
  const int brow = tn * 128 + srow;

  f4 acc[4][4];
#pragma unroll
  for (int i = 0; i < 4; ++i)
#pragma unroll
    for (int j = 0; j < 4; ++j) acc[i][j] = (f4)0.f;

  for (int k0 = 0; k0 < K; k0 += 64) {
    uint4 va[4], vb[4];
    const uint4* gpa = (const uint4*)(A + (size_t)arow * K + k0 + seg * 32);
    const uint4* gpb = (const uint4*)(B + (size_t)brow * K + k0 + seg * 32);
#pragma unroll
    for (int c = 0; c < 4; ++c) va[c] = gpa[c];
#pragma unroll
    for (int c = 0; c < 4; ++c) vb[c] = gpb[c];

    __syncthreads();  // previous compute done before overwriting LDS
    uint4* lpa = (uint4*)&As[srow * LSTR + seg * 32];
    uint4* lpb = (uint4*)&Bs[srow * LSTR + seg * 32];
#pragma unroll
    for (int c = 0; c < 4; ++c) lpa[c] = va[c];
#pragma unroll
    for (int c = 0; c < 4; ++c) lpb[c] = vb[c];
    __syncthreads();

#pragma unroll
    for (int kk = 0; kk < 64; kk += 32) {
      h8 af[4], bf[4];
#pragma unroll
      for (int i = 0; i < 4; ++i) {
        int m = wr * 64 + i * 16 + l16;
        af[i] = *(const h8*)&As[m * LSTR + kk + quad * 8];
        int n = wc * 64 + i * 16 + l16;
        bf[i] = *(const h8*)&Bs[n * LSTR + kk + quad * 8];
      }
#pragma unroll
      for (int i = 0; i < 4; ++i)
#pragma unroll
        for (int j = 0; j < 4; ++j)
          acc[i][j] = __builtin_amdgcn_mfma_f32_16x16x32_f16(af[i], bf[j], acc[i][j], 0, 0, 0);
    }
  }

  const int cm0 = tm * 128 + wr * 64, cn0 = tn * 128 + wc * 64;
#pragma unroll
  for (int i = 0; i < 4; ++i) {
#pragma unroll
    for (int j = 0; j < 4; ++j) {
      int n = cn0 + j * 16 + l16;
#pragma unroll
      for (int r = 0; r < 4; ++r) {
        int m = cm0 + i * 16 + quad * 4 + r;
        float v = acc[i][j][r];
        if (MODE == 0) {
          v += bias1[n] + bias2[n];
          ((_Float16*)Cout)[(size_t)m * N + n] = (_Float16)v;
        } else {
          if (n < nout) ((float*)Cout)[(size_t)m * nout + n] = v + bias1[n];
        }
      }
    }
  }
}

// ---------------------------------------------------------------------------
// Persistent bidirectional LSTM recurrence.
// 128 blocks x 256 threads. blk<64: forward dir; blk>=64: backward dir.
// Block owns 16 h-outputs (j0..j0+15) => 64 W_hh rows (4 gates x 16).
// Thread (tid): row-local rl=tid>>2 (gate=rl>>4, jj=rl&15), k-quarter kq=tid&3.
// W slice: 256 f16 = 128 half2 in registers.
// Sync: flags[blk] = #completed steps (agent-scope); consumers poll all 64
// flags of their direction with one wave64 load. h ping-pongs between 2 bufs.
// ---------------------------------------------------------------------------
__global__ __launch_bounds__(256, 1) void lstm_rec(
    const float* __restrict__ Whh_f, const float* __restrict__ Whh_b,
    const _Float16* __restrict__ xp,  // [2][2048][4096] f16 (incl. biases)
    float* __restrict__ hbuf,         // [2 bufs][2 dirs][1024]
    int* __restrict__ flags,          // [128]
    _Float16* __restrict__ hhist) {   // [2048][2048] f16 (fwd | bwd)
  const int tid = threadIdx.x;
  const int blk = blockIdx.x;
  const int dir = blk >> 6;
  const int ib = blk & 63;
  const int j0 = ib * 16;
  const int kq = tid & 3;
  const int rl = tid >> 2;
  const int jj = rl & 15;
  const int gate = rl >> 4;
  const int wrow = gate * 1024 + j0 + jj;

  const float* Whh = dir ? Whh_b : Whh_f;
  const _Float16* xpd = xp + (size_t)dir * (2048u * 4096u);

  __shared__ unsigned int lds_h[512];  // h as half2
  __shared__ float gates_lds[64];
  __shared__ float c_lds[16];

  // one-time: W_hh rows -> f16 registers
  unsigned int w[128];
  {
    const float* wp = Whh + (size_t)wrow * 1024 + kq * 256;
#pragma unroll
    for (int i = 0; i < 64; ++i) {
      float4 v = ((const float4*)wp)[i];
      w[2 * i] = packh2(v.x, v.y);
      w[2 * i + 1] = packh2(v.z, v.w);
    }
  }
  if (tid < 16) c_lds[tid] = 0.f;
  __syncthreads();

  float* hA = hbuf + dir * 1024;         // buffer read on even t
  float* hB = hbuf + 2048 + dir * 1024;  // buffer read on odd t

  for (int t = 0; t < T_LEN; ++t) {
    // prefetch x_proj for this step's row (covers poll latency)
    float xpv = (float)xpd[(size_t)t * 4096 + wrow];

    // wave 0 polls all 64 producer flags of this direction
    if (tid < 64) {
      int cnt = 0;
      while (true) {
        int v = __hip_atomic_load(&flags[dir * 64 + tid], __ATOMIC_ACQUIRE,
                                  __HIP_MEMORY_SCOPE_AGENT);
        if (__all(v >= t)) break;
        if (++cnt > (1 << 13)) break;  // bailout: fail-absmax instead of hang
      }
    }
    __syncthreads();

    // load h[1024] (fp32, agent-coherent) -> LDS half2
    {
      float* hsrc = (t & 1) ? hB : hA;
      float f0 = __hip_atomic_load(&hsrc[4 * tid + 0], __ATOMIC_RELAXED, __HIP_MEMORY_SCOPE_AGENT);
      float f1 = __hip_atomic_load(&hsrc[4 * tid + 1], __ATOMIC_RELAXED, __HIP_MEMORY_SCOPE_AGENT);
      float f2 = __hip_atomic_load(&hsrc[4 * tid + 2], __ATOMIC_RELAXED, __HIP_MEMORY_SCOPE_AGENT);
      float f3 = __hip_atomic_load(&hsrc[4 * tid + 3], __ATOMIC_RELAXED, __HIP_MEMORY_SCOPE_AGENT);
      lds_h[2 * tid] = packh2(f0, f1);
      lds_h[2 * tid + 1] = packh2(f2, f3);
    }
    __syncthreads();

    // dot: this thread's 256-element k-slice of its row
    float acc = 0.f;
    const uint4* hp = (const uint4*)&lds_h[kq * 128];
#pragma unroll
    for (int i = 0; i < 32; ++i) {
      uint4 hv = hp[i];
      acc = fdot2u(w[4 * i + 0], hv.x, acc);
      acc = fdot2u(w[4 * i + 1], hv.y, acc);
      acc = fdot2u(w[4 * i + 2], hv.z, acc);
      acc = fdot2u(w[4 * i + 3], hv.w, acc);
    }
    // reduce 4 k-quarters (adjacent lanes)
    acc += __shfl_xor(acc, 1, 64);
    acc += __shfl_xor(acc, 2, 64);
    if (kq == 0) gates_lds[rl] = acc + xpv;
    __syncthreads();

    // elementwise LSTM cell (16 lanes of wave 0)
    if (tid < 16) {
      float ig = sigmoidf_(gates_lds[tid]);
      float fg = sigmoidf_(gates_lds[16 + tid]);
      float gg = tanhf_(gates_lds[32 + tid]);
      float og = sigmoidf_(gates_lds[48 + tid]);
      float c = fg * c_lds[tid] + ig * gg;
      c_lds[tid] = c;
      float h = og * tanhf_(c);
      float* hdst = (t & 1) ? hA : hB;  // written buffer is read at t+1
      __hip_atomic_store(&hdst[j0 + tid], h, __ATOMIC_RELAXED, __HIP_MEMORY_SCOPE_AGENT);
      int tout = dir ? (T_LEN - 1 - t) : t;
      hhist[(size_t)tout * 2048 + dir * 1024 + j0 + tid] = (_Float16)h;
    }
    if (tid == 0) {
      // release: waits this wave's h/hhist stores, then publishes step count
      __hip_atomic_store(&flags[blk], t + 1, __ATOMIC_RELEASE, __HIP_MEMORY_SCOPE_AGENT);
    }
    // next iteration's first __syncthreads orders LDS reuse
  }
}

// ---------------------------------------------------------------------------
extern "C" void kernel_launch(void* const* d_in, const int* in_sizes, int n_in,
                              void* d_out, int out_size, void* d_ws, size_t ws_size,
                              hipStream_t stream) {
  (void)in_sizes; (void)n_in; (void)out_size; (void)ws_size;
  const float* x     = (const float*)d_in[0];
  const float* Wih_f = (const float*)d_in[1];
  const float* Whh_f = (const float*)d_in[2];
  const float* bih_f = (const float*)d_in[3];
  const float* bhh_f = (const float*)d_in[4];
  const float* Wih_b = (const float*)d_in[5];
  const float* Whh_b = (const float*)d_in[6];
  const float* bih_b = (const float*)d_in[7];
  const float* bhh_b = (const float*)d_in[8];
  const float* fcW   = (const float*)d_in[9];
  const float* fcb   = (const float*)d_in[10];

  char* ws = (char*)d_ws;
  _Float16* xf16   = (_Float16*)(ws + 0);
  _Float16* wih16f = (_Float16*)(ws + 4194304);
  _Float16* wih16b = (_Float16*)(ws + 12582912);
  _Float16* fcw16  = (_Float16*)(ws + 20971520);
  _Float16* xp16   = (_Float16*)(ws + 25165824);   // [2][2048][4096]
  _Float16* hhist  = (_Float16*)(ws + 58720256);   // [2048][2048]
  float*    hbuf   = (float*)   (ws + 67108864);   // [2][2][1024]
  int*      flags  = (int*)     (ws + 67125248);   // [128]

  const size_t SX = 2097152, SW = 4194304, SFC = 2097152;
  const size_t total_cvt = SX + 2 * SW + SFC;

  convert_all<<<dim3((unsigned)((total_cvt + 255) / 256)), 256, 0, stream>>>(
      x, Wih_f, Wih_b, fcW, xf16, wih16f, wih16b, fcw16);
  init_state<<<1, 256, 0, stream>>>(hbuf, flags);

  // input projections: M=2048, N=4096, K=1024; dir1 consumes reversed x rows
  gemm_f16<0><<<dim3(512), 256, 0, stream>>>(xf16, wih16f, bih_f, bhh_f,
                                             (void*)xp16, 2048, 4096, 1024, 4096, 0);
  gemm_f16<0><<<dim3(512), 256, 0, stream>>>(xf16, wih16b, bih_b, bhh_b,
                                             (void*)(xp16 + (size_t)2048 * 4096),
                                             2048, 4096, 1024, 4096, 1);

  lstm_rec<<<dim3(128), 256, 0, stream>>>(Whh_f, Whh_b, xp16, hbuf, flags, hhist);

  // FC: M=2048, N=1024 (1000 valid), K=2048
  gemm_f16<1><<<dim3(128), 256, 0, stream>>>(hhist, fcw16, fcb, nullptr,
                                             d_out, 2048, 1024, 2048, 1000, 0);
}

// Round 3
// 4369.816 us; speedup vs baseline: 3.1212x; 3.1212x over previous
//
#include <hip/hip_runtime.h>
#include <hip/hip_bf16.h>
#include <cstdint>

// ---------------------------------------------------------------------------
// BiLSTM: x[2048,1024] -> bidirectional LSTM (H=1024) -> FC to 1000 classes.
//   1. convert_all: fp32 -> f16 copies of x, W_ih_f, W_ih_b, fc_W
//   2. gemm_f16<0>: x_proj_d = x_d @ W_ih_d^T + b_ih + b_hh   (f16 MFMA)
//   3. lstm_rec: persistent, 128 blocks (64/dir), W_hh slice in registers.
//      R3: seq-embedded h publication (one LLC round trip/step):
//      each 4-h group = two u64 words [h01|seq] and [seq|h23]; 64-bit atomics
//      are single-copy atomic, so a retry-load validates data+seq together.
//      Gen-parity ping-pong (2 bufs) keeps skew-safety (every consumer is a
//      producer, so gen G can't be overwritten by G+2 before all read G).
//      LDS h staged with segment stride 36 (kills 4-way bank conflict of R2),
//      dot = 4 rows/thread x 64-k slice (4x fewer ds_read_b128 per CU).
//   4. gemm_f16<1>: out = h_hist @ fc_W^T + fc_b
// ---------------------------------------------------------------------------

typedef __fp16 h2 __attribute__((ext_vector_type(2)));
typedef __fp16 h8 __attribute__((ext_vector_type(8)));
typedef float f4 __attribute__((ext_vector_type(4)));
typedef unsigned long long u64;

#define T_LEN 2048

static __device__ __forceinline__ unsigned int packh2(float a, float b) {
  h2 r = __builtin_amdgcn_cvt_pkrtz(a, b);
  return __builtin_bit_cast(unsigned int, r);
}
static __device__ __forceinline__ float fdot2u(unsigned int a, unsigned int b, float c) {
  return __builtin_amdgcn_fdot2(__builtin_bit_cast(h2, a), __builtin_bit_cast(h2, b), c, false);
}
static __device__ __forceinline__ float sigmoidf_(float x) {
  return 1.f / (1.f + __expf(-x));
}
static __device__ __forceinline__ float tanhf_(float x) {
  float e = __expf(-2.f * fabsf(x));
  float r = (1.f - e) / (1.f + e);
  return copysignf(r, x);
}

// ---------------------------------------------------------------------------
__global__ void convert_all(const float* __restrict__ x, const float* __restrict__ wf,
                            const float* __restrict__ wb, const float* __restrict__ fcw,
                            _Float16* __restrict__ xf, _Float16* __restrict__ wff,
                            _Float16* __restrict__ wbf, _Float16* __restrict__ fcwf) {
  const size_t SX = 2097152, SW = 4194304, SFC = 2097152;
  size_t i = (size_t)blockIdx.x * 256 + threadIdx.x;
  if (i < SX) {
    xf[i] = (_Float16)x[i];
  } else if (i < SX + SW) {
    size_t j = i - SX; wff[j] = (_Float16)wf[j];
  } else if (i < SX + 2 * SW) {
    size_t j = i - SX - SW; wbf[j] = (_Float16)wb[j];
  } else if (i < SX + 2 * SW + SFC) {
    size_t j = i - SX - 2 * SW;
    int row = (int)(j >> 11), col = (int)(j & 2047);
    fcwf[j] = (row < 1000) ? (_Float16)fcw[(size_t)row * 2048 + col] : (_Float16)0.f;
  }
}

// zero the h-communication buffers: gen 0 == valid zeros for t=0
__global__ void init_state(u64* __restrict__ hc) {
  int t = threadIdx.x;
  for (int i = t; i < 2048; i += 256) hc[i] = 0ull;
}

// ---------------------------------------------------------------------------
// f16 GEMM, 128x128 tile, BK=64 (unchanged from R2 — passed correctness)
// ---------------------------------------------------------------------------
#define LSTR 80

template <int MODE>
__global__ __launch_bounds__(256, 2) void gemm_f16(
    const _Float16* __restrict__ A, const _Float16* __restrict__ B,
    const float* __restrict__ bias1, const float* __restrict__ bias2,
    void* __restrict__ Cout, int M, int N, int K, int nout, int rev) {
  __shared__ _Float16 As[128 * LSTR];
  __shared__ _Float16 Bs[128 * LSTR];

  const int tid = threadIdx.x;
  const int ntn = N >> 7;
  const int tm = blockIdx.x / ntn, tn = blockIdx.x % ntn;
  const int wid = tid >> 6, lane = tid & 63;
  const int wr = wid >> 1, wc = wid & 1;
  const int quad = lane >> 4, l16 = lane & 15;

  const int srow = tid >> 1, seg = tid & 1;
  const int arow = rev ? (M - 1 - (tm * 128 + srow)) : (tm * 128 + srow);
  const int brow = tn * 128 + srow;

  f4 acc[4][4];
#pragma unroll
  for (int i = 0; i < 4; ++i)
#pragma unroll
    for (int j = 0; j < 4; ++j) acc[i][j] = (f4)0.f;

  for (int k0 = 0; k0 < K; k0 += 64) {
    uint4 va[4], vb[4];
    const uint4* gpa = (const uint4*)(A + (size_t)arow * K + k0 + seg * 32);
    const uint4* gpb = (const uint4*)(B + (size_t)brow * K + k0 + seg * 32);
#pragma unroll
    for (int c = 0; c < 4; ++c) va[c] = gpa[c];
#pragma unroll
    for (int c = 0; c < 4; ++c) vb[c] = gpb[c];

    __syncthreads();
    uint4* lpa = (uint4*)&As[srow * LSTR + seg * 32];
    uint4* lpb = (uint4*)&Bs[srow * LSTR + seg * 32];
#pragma unroll
    for (int c = 0; c < 4; ++c) lpa[c] = va[c];
#pragma unroll
    for (int c = 0; c < 4; ++c) lpb[c] = vb[c];
    __syncthreads();

#pragma unroll
    for (int kk = 0; kk < 64; kk += 32) {
      h8 af[4], bf[4];
#pragma unroll
      for (int i = 0; i < 4; ++i) {
        int m = wr * 64 + i * 16 + l16;
        af[i] = *(const h8*)&As[m * LSTR + kk + quad * 8];
        int n = wc * 64 + i * 16 + l16;
        bf[i] = *(const h8*)&Bs[n * LSTR + kk + quad * 8];
      }
#pragma unroll
      for (int i = 0; i < 4; ++i)
#pragma unroll
        for (int j = 0; j < 4; ++j)
          acc[i][j] = __builtin_amdgcn_mfma_f32_16x16x32_f16(af[i], bf[j], acc[i][j], 0, 0, 0);
    }
  }

  const int cm0 = tm * 128 + wr * 64, cn0 = tn * 128 + wc * 64;
#pragma unroll
  for (int i = 0; i < 4; ++i) {
#pragma unroll
    for (int j = 0; j < 4; ++j) {
      int n = cn0 + j * 16 + l16;
#pragma unroll
      for (int r = 0; r < 4; ++r) {
        int m = cm0 + i * 16 + quad * 4 + r;
        float v = acc[i][j][r];
        if (MODE == 0) {
          v += bias1[n] + bias2[n];
          ((_Float16*)Cout)[(size_t)m * N + n] = (_Float16)v;
        } else {
          if (n < nout) ((float*)Cout)[(size_t)m * nout + n] = v + bias1[n];
        }
      }
    }
  }
}

// ---------------------------------------------------------------------------
// Persistent BiLSTM recurrence, seq-embedded h publication.
// 128 blocks x 256 thr. blk<64 fwd, else bwd. Block owns 16 h (j0..j0+15)
// = 64 W_hh rows. Thread: rg=tid>>4 (4 rows: r0=4*rg..+3, same gate),
// kq2=tid&15 (64-elem k-slice). W regs: 4x64 f16 = 128 dwords.
// hc layout: [buf][dir][256 grp][2] u64; group g = h[4g..4g+3]:
//   word0 = (u64)h2(h0,h1)<<32 | seq ; word1 = (u64)seq<<32 | h2(h2,h3)
// Consumer of step t polls buf t&1 until both seq fields == t (init zeros
// serve t=0). Producer publishes seq=t+1 into buf (t+1)&1.
// ---------------------------------------------------------------------------
__global__ __launch_bounds__(256, 1) void lstm_rec(
    const float* __restrict__ Whh_f, const float* __restrict__ Whh_b,
    const _Float16* __restrict__ xp,   // [2][2048][4096]
    u64* __restrict__ hc,              // [2][2][256][2]
    _Float16* __restrict__ hhist) {    // [2048][2048]
  const int tid = threadIdx.x;
  const int blk = blockIdx.x;
  const int dir = blk >> 6;
  const int ib = blk & 63;
  const int j0 = ib * 16;
  const int kq2 = tid & 15;
  const int rg = tid >> 4;
  const int r0 = 4 * rg;                  // block-local rows r0..r0+3
  const int gate = rg >> 2;
  const int wrow0 = gate * 1024 + j0 + (r0 & 15);  // 4 consecutive W rows

  const float* Whh = dir ? Whh_b : Whh_f;
  const _Float16* xpd = xp + (size_t)dir * (2048u * 4096u);

  __shared__ unsigned int lds_h[16 * 36];  // 16 k-segments, stride 36 (pad)
  __shared__ float gates_lds[64];

  // one-time: W_hh[wrow0..+3][kq2*64..+63] -> f16 regs
  unsigned int w[4][32];
#pragma unroll
  for (int j = 0; j < 4; ++j) {
    const float* wp = Whh + (size_t)(wrow0 + j) * 1024 + kq2 * 64;
#pragma unroll
    for (int i = 0; i < 16; ++i) {
      float4 v = ((const float4*)wp)[i];
      w[j][2 * i] = packh2(v.x, v.y);
      w[j][2 * i + 1] = packh2(v.z, v.w);
    }
  }

  float c = 0.f;  // cell state lives in lanes tid<16 of wave 0

  for (int t = 0; t < T_LEN; ++t) {
    // prefetch x_proj for this thread's 4 rows (consecutive f16, 8B)
    uint2 xv = *(const uint2*)(xpd + (size_t)t * 4096 + wrow0);
    h2 x01 = __builtin_bit_cast(h2, xv.x);
    h2 x23 = __builtin_bit_cast(h2, xv.y);
    float xf[4] = {(float)x01[0], (float)x01[1], (float)x23[0], (float)x23[1]};

    // retry-load own h group g=tid from buf t&1 until seq fields == t
    {
      u64* src = hc + ((((size_t)(t & 1) * 2 + dir) * 256 + tid) * 2);
      u64 a = __hip_atomic_load(&src[0], __ATOMIC_RELAXED, __HIP_MEMORY_SCOPE_AGENT);
      u64 b = __hip_atomic_load(&src[1], __ATOMIC_RELAXED, __HIP_MEMORY_SCOPE_AGENT);
      int cnt = 0;
      while ((unsigned)a != (unsigned)t || (unsigned)(b >> 32) != (unsigned)t) {
        if (++cnt > (1 << 13)) break;  // bailout: fail absmax, never hang
        a = __hip_atomic_load(&src[0], __ATOMIC_RELAXED, __HIP_MEMORY_SCOPE_AGENT);
        b = __hip_atomic_load(&src[1], __ATOMIC_RELAXED, __HIP_MEMORY_SCOPE_AGENT);
      }
      int seg = tid >> 4, lo = (tid & 15) * 2;
      lds_h[seg * 36 + lo] = (unsigned)(a >> 32);
      lds_h[seg * 36 + lo + 1] = (unsigned)b;
    }
    __syncthreads();

    // dot: 4 rows x 64-elem slice; 8 ds_read_b128, 128 fdot2
    float acc[4] = {0.f, 0.f, 0.f, 0.f};
    const uint4* hp = (const uint4*)&lds_h[kq2 * 36];
#pragma unroll
    for (int i = 0; i < 8; ++i) {
      uint4 hv = hp[i];
#pragma unroll
      for (int j = 0; j < 4; ++j) {
        acc[j] = fdot2u(w[j][4 * i + 0], hv.x, acc[j]);
        acc[j] = fdot2u(w[j][4 * i + 1], hv.y, acc[j]);
        acc[j] = fdot2u(w[j][4 * i + 2], hv.z, acc[j]);
        acc[j] = fdot2u(w[j][4 * i + 3], hv.w, acc[j]);
      }
    }
    // reduce across 16 k-slices (kq2 = lane&15)
#pragma unroll
    for (int m = 1; m < 16; m <<= 1) {
      acc[0] += __shfl_xor(acc[0], m, 64);
      acc[1] += __shfl_xor(acc[1], m, 64);
      acc[2] += __shfl_xor(acc[2], m, 64);
      acc[3] += __shfl_xor(acc[3], m, 64);
    }
    if (kq2 == 0) {
#pragma unroll
      for (int j = 0; j < 4; ++j) gates_lds[r0 + j] = acc[j] + xf[j];
    }
    __syncthreads();

    // cell + publish (wave 0, lanes < 16)
    if (tid < 16) {
      float ii = sigmoidf_(gates_lds[tid]);
      float ff = sigmoidf_(gates_lds[16 + tid]);
      float gg = tanhf_(gates_lds[32 + tid]);
      float oo = sigmoidf_(gates_lds[48 + tid]);
      c = ff * c + ii * gg;
      float h = oo * tanhf_(c);

      // gather quads to lanes 0..3 and publish (seq-embedded, relaxed)
      float h0 = __shfl(h, 4 * tid + 0, 64);
      float h1 = __shfl(h, 4 * tid + 1, 64);
      float h2v = __shfl(h, 4 * tid + 2, 64);
      float h3 = __shfl(h, 4 * tid + 3, 64);
      if (tid < 4) {
        unsigned u01 = packh2(h0, h1);
        unsigned u23 = packh2(h2v, h3);
        u64 w0 = ((u64)u01 << 32) | (unsigned)(t + 1);
        u64 w1 = ((u64)(unsigned)(t + 1) << 32) | u23;
        u64* dst = hc + ((((size_t)((t + 1) & 1) * 2 + dir) * 256 + (ib * 4 + tid)) * 2);
        __hip_atomic_store(&dst[0], w0, __ATOMIC_RELAXED, __HIP_MEMORY_SCOPE_AGENT);
        __hip_atomic_store(&dst[1], w1, __ATOMIC_RELAXED, __HIP_MEMORY_SCOPE_AGENT);
      }
      // hhist store AFTER publish: off the critical sync path
      int tout = dir ? (T_LEN - 1 - t) : t;
      hhist[(size_t)tout * 2048 + dir * 1024 + j0 + tid] = (_Float16)h;
    }
    // next iteration's first __syncthreads orders lds_h reuse
  }
}

// ---------------------------------------------------------------------------
extern "C" void kernel_launch(void* const* d_in, const int* in_sizes, int n_in,
                              void* d_out, int out_size, void* d_ws, size_t ws_size,
                              hipStream_t stream) {
  (void)in_sizes; (void)n_in; (void)out_size; (void)ws_size;
  const float* x     = (const float*)d_in[0];
  const float* Wih_f = (const float*)d_in[1];
  const float* Whh_f = (const float*)d_in[2];
  const float* bih_f = (const float*)d_in[3];
  const float* bhh_f = (const float*)d_in[4];
  const float* Wih_b = (const float*)d_in[5];
  const float* Whh_b = (const float*)d_in[6];
  const float* bih_b = (const float*)d_in[7];
  const float* bhh_b = (const float*)d_in[8];
  const float* fcW   = (const float*)d_in[9];
  const float* fcb   = (const float*)d_in[10];

  char* ws = (char*)d_ws;
  _Float16* xf16   = (_Float16*)(ws + 0);
  _Float16* wih16f = (_Float16*)(ws + 4194304);
  _Float16* wih16b = (_Float16*)(ws + 12582912);
  _Float16* fcw16  = (_Float16*)(ws + 20971520);
  _Float16* xp16   = (_Float16*)(ws + 25165824);   // [2][2048][4096]
  _Float16* hhist  = (_Float16*)(ws + 58720256);   // [2048][2048]
  u64*      hc     = (u64*)     (ws + 67108864);   // [2][2][256][2]

  const size_t SX = 2097152, SW = 4194304, SFC = 2097152;
  const size_t total_cvt = SX + 2 * SW + SFC;

  convert_all<<<dim3((unsigned)((total_cvt + 255) / 256)), 256, 0, stream>>>(
      x, Wih_f, Wih_b, fcW, xf16, wih16f, wih16b, fcw16);
  init_state<<<1, 256, 0, stream>>>(hc);

  gemm_f16<0><<<dim3(512), 256, 0, stream>>>(xf16, wih16f, bih_f, bhh_f,
                                             (void*)xp16, 2048, 4096, 1024, 4096, 0);
  gemm_f16<0><<<dim3(512), 256, 0, stream>>>(xf16, wih16b, bih_b, bhh_b,
                                             (void*)(xp16 + (size_t)2048 * 4096),
                                             2048, 4096, 1024, 4096, 1);

  lstm_rec<<<dim3(128), 256, 0, stream>>>(Whh_f, Whh_b, xp16, hc, hhist);

  gemm_f16<1><<<dim3(128), 256, 0, stream>>>(hhist, fcw16, fcb, nullptr,
                                             d_out, 2048, 1024, 2048, 1000, 0);
}